// Round 7
// baseline (487.096 us; speedup 1.0000x reference)
//
#include <hip/hip_runtime.h>
#include <cmath>

#define NN 8192

typedef _Float16 half8 __attribute__((ext_vector_type(8)));
typedef float floatx4 __attribute__((ext_vector_type(4)));
typedef unsigned int uint;

// ---------------------------------------------------------------------------
// h_kernel<L2>: H[ch] = X @ w_ch, output fp16 in MFMA B-fragment order:
//   Hfrag[ch][t][tile][lane][elem], t=j>>5, lane=(n&15)|(((j&31)>>3)<<4),
//   tile=n>>4, elem=j&7.
// L2=0: X = V (f32 [8192,32]).  L2=1: X = relu(sum_{c<8} Zpart[c] + gbias).
// Grid dim3(128,3): blockIdx.y = channel, block owns 64 rows of X.
// ---------------------------------------------------------------------------
template <int L2>
__global__ __launch_bounds__(256) void h_kernel(
    const float* __restrict__ X, const float* __restrict__ w1,
    const float* __restrict__ w2, const float* __restrict__ w3,
    const float* __restrict__ gbias, _Float16* __restrict__ Hfrag) {
  __shared__ float wl[32][32];   // wl[d][n]
  __shared__ float Xs[64][32];
  const int tid = threadIdx.x;
  const int ch = blockIdx.y;
  const float* wsrc = (ch == 0) ? w1 : (ch == 1) ? w2 : w3;
  for (int i = tid; i < 1024; i += 256) ((float*)wl)[i] = wsrc[i];
  const size_t base = (size_t)blockIdx.x * 2048 + tid * 8;
  if (L2 == 0) {
    float4 x0 = ((const float4*)(X + base))[0];
    float4 x1 = ((const float4*)(X + base))[1];
    *((float4*)(&Xs[0][0] + tid * 8)) = x0;
    *((float4*)(&Xs[0][0] + tid * 8 + 4)) = x1;
  } else {
    float4 s0 = {0.f, 0.f, 0.f, 0.f}, s1 = {0.f, 0.f, 0.f, 0.f};
#pragma unroll
    for (int c = 0; c < 8; ++c) {
      const float4* p = (const float4*)(X + (size_t)c * NN * 32 + base);
      float4 a = p[0], b = p[1];
      s0.x += a.x; s0.y += a.y; s0.z += a.z; s0.w += a.w;
      s1.x += b.x; s1.y += b.y; s1.z += b.z; s1.w += b.w;
    }
    const int c0 = (tid * 8) & 31;
    const float4 b0 = *(const float4*)(gbias + c0);
    const float4 b1 = *(const float4*)(gbias + c0 + 4);
    s0.x += b0.x; s0.y += b0.y; s0.z += b0.z; s0.w += b0.w;
    s1.x += b1.x; s1.y += b1.y; s1.z += b1.z; s1.w += b1.w;
    s0.x = s0.x > 0.f ? s0.x : 0.f; s0.y = s0.y > 0.f ? s0.y : 0.f;
    s0.z = s0.z > 0.f ? s0.z : 0.f; s0.w = s0.w > 0.f ? s0.w : 0.f;
    s1.x = s1.x > 0.f ? s1.x : 0.f; s1.y = s1.y > 0.f ? s1.y : 0.f;
    s1.z = s1.z > 0.f ? s1.z : 0.f; s1.w = s1.w > 0.f ? s1.w : 0.f;
    *((float4*)(&Xs[0][0] + tid * 8)) = s0;
    *((float4*)(&Xs[0][0] + tid * 8 + 4)) = s1;
  }
  __syncthreads();
  const int n = tid & 31, jb = tid >> 5;
  const int j0 = blockIdx.x * 64 + jb * 8;
  const int t = j0 >> 5;
  const int lane = (n & 15) | (((j0 & 31) >> 3) << 4);
  const int tile = n >> 4;
  half8 hv;
#pragma unroll
  for (int jj = 0; jj < 8; ++jj) {
    const float4* xr = (const float4*)(&Xs[jb * 8 + jj][0]);
    float acc = 0.f;
#pragma unroll
    for (int d4 = 0; d4 < 8; ++d4) {
      float4 x = xr[d4];
      acc += x.x * wl[d4 * 4 + 0][n];
      acc += x.y * wl[d4 * 4 + 1][n];
      acc += x.z * wl[d4 * 4 + 2][n];
      acc += x.w * wl[d4 * 4 + 3][n];
    }
    hv[jj] = (_Float16)acc;
  }
  size_t idx = ((((size_t)ch * 256 + t) * 2 + tile) * 64 + lane) * 8;
  *(half8*)(Hfrag + idx) = hv;
}

// ---------------------------------------------------------------------------
// Phase B: masks from the LDS packed tile ptile[tg:8][lane:64][t4:4]
// (uint32 = row-group0 bits | row-group1 bits << 16), exact A-fragment
// consume order. Wave w handles k-tiles w*8..w*8+7 of the block's 1024-j
// chunk, M=32 rows (two 16-row tiles sharing B fragments). Writes raw
// partial sums to Zpart[c][row][32] (C/D: col=lane&15, row=(lane>>4)*4+reg).
// red_lds (16 KB) aliases ptile (8 KB): masks are register-resident before
// the barrier that precedes any red write. (Verified rounds 4/5.)
// ---------------------------------------------------------------------------
__device__ __forceinline__ void agg_phaseB(const uint* ptile, float* red_raw,
                                           const half8* __restrict__ Hf,
                                           float* __restrict__ Zpart, int rg,
                                           int c, int tid) {
  const int w = tid >> 6, lane = tid & 63;
  const int m = lane & 15, q = lane >> 4;
  uint mk[8];
  *(uint4*)(mk) = *(const uint4*)(ptile + (w * 2) * 256 + lane * 4);
  *(uint4*)(mk + 4) = *(const uint4*)(ptile + (w * 2 + 1) * 256 + lane * 4);
  __syncthreads();  // masks in regs; safe for red to alias ptile after this
  floatx4 acc00 = {0.f, 0.f, 0.f, 0.f}, acc01 = {0.f, 0.f, 0.f, 0.f};
  floatx4 acc10 = {0.f, 0.f, 0.f, 0.f}, acc11 = {0.f, 0.f, 0.f, 0.f};
#pragma unroll 2
  for (int tl = 0; tl < 8; ++tl) {
    const int t = c * 32 + w * 8 + tl;  // global k-tile index
    const size_t hb = (size_t)t * 128 + lane;
    half8 b00 = Hf[hb],          b01 = Hf[hb + 64];
    half8 b10 = Hf[hb + 32768],  b11 = Hf[hb + 32768 + 64];
    half8 b20 = Hf[hb + 65536],  b21 = Hf[hb + 65536 + 64];
    const uint pk = mk[tl];
    half8 a1r0, a2r0, a3r0, a1r1, a2r1, a3r1;
#pragma unroll
    for (int i = 0; i < 8; ++i) {
      const int p0 = (pk >> (2 * i)) & 3;
      const int p1 = (pk >> (16 + 2 * i)) & 3;
      a1r0[i] = (p0 == 1) ? (_Float16)1.f : (_Float16)0.f;
      a2r0[i] = (p0 == 2) ? (_Float16)1.f : (_Float16)0.f;
      a3r0[i] = (p0 == 3) ? (_Float16)1.f : (_Float16)0.f;
      a1r1[i] = (p1 == 1) ? (_Float16)1.f : (_Float16)0.f;
      a2r1[i] = (p1 == 2) ? (_Float16)1.f : (_Float16)0.f;
      a3r1[i] = (p1 == 3) ? (_Float16)1.f : (_Float16)0.f;
    }
    acc00 = __builtin_amdgcn_mfma_f32_16x16x32_f16(a1r0, b00, acc00, 0, 0, 0);
    acc00 = __builtin_amdgcn_mfma_f32_16x16x32_f16(a2r0, b10, acc00, 0, 0, 0);
    acc00 = __builtin_amdgcn_mfma_f32_16x16x32_f16(a3r0, b20, acc00, 0, 0, 0);
    acc01 = __builtin_amdgcn_mfma_f32_16x16x32_f16(a1r0, b01, acc01, 0, 0, 0);
    acc01 = __builtin_amdgcn_mfma_f32_16x16x32_f16(a2r0, b11, acc01, 0, 0, 0);
    acc01 = __builtin_amdgcn_mfma_f32_16x16x32_f16(a3r0, b21, acc01, 0, 0, 0);
    acc10 = __builtin_amdgcn_mfma_f32_16x16x32_f16(a1r1, b00, acc10, 0, 0, 0);
    acc10 = __builtin_amdgcn_mfma_f32_16x16x32_f16(a2r1, b10, acc10, 0, 0, 0);
    acc10 = __builtin_amdgcn_mfma_f32_16x16x32_f16(a3r1, b20, acc10, 0, 0, 0);
    acc11 = __builtin_amdgcn_mfma_f32_16x16x32_f16(a1r1, b01, acc11, 0, 0, 0);
    acc11 = __builtin_amdgcn_mfma_f32_16x16x32_f16(a2r1, b11, acc11, 0, 0, 0);
    acc11 = __builtin_amdgcn_mfma_f32_16x16x32_f16(a3r1, b21, acc11, 0, 0, 0);
  }
  // combine the 4 waves' j-slices through LDS
  float (*red)[4][64][4] = (float (*)[4][64][4])red_raw;
#pragma unroll
  for (int r = 0; r < 4; ++r) {
    red[w][0][lane][r] = acc00[r];
    red[w][1][lane][r] = acc01[r];
    red[w][2][lane][r] = acc10[r];
    red[w][3][lane][r] = acc11[r];
  }
  __syncthreads();
  if (w == 0) {
    const int rbase = rg * 32;
#pragma unroll
    for (int r = 0; r < 4; ++r) {
      const float c00 = red[0][0][lane][r] + red[1][0][lane][r] +
                        red[2][0][lane][r] + red[3][0][lane][r];
      const float c01 = red[0][1][lane][r] + red[1][1][lane][r] +
                        red[2][1][lane][r] + red[3][1][lane][r];
      const float c10 = red[0][2][lane][r] + red[1][2][lane][r] +
                        red[2][2][lane][r] + red[3][2][lane][r];
      const float c11 = red[0][3][lane][r] + red[1][3][lane][r] +
                        red[2][3][lane][r] + red[3][3][lane][r];
      const int ro0 = rbase + q * 4 + r;
      float* zp0 = Zpart + ((size_t)c * NN + ro0) * 32;
      zp0[m] = c00;
      zp0[16 + m] = c01;
      float* zp1 = Zpart + ((size_t)c * NN + ro0 + 16) * 32;
      zp1[m] = c10;
      zp1[16 + m] = c11;
    }
  }
}

// ---------------------------------------------------------------------------
// agg_kernel (fused, used for BOTH layers): block (rg,c) reads adj rows
// rg*32..+32, j c*1024..+1024 with contiguous dwordx4 loads, 8 rows in
// flight per thread (128 B/thread outstanding -> ~256 KB/CU MLP), packs
// 2-bit codes into the 8 KB LDS consume-order tile (verified layout:
//   dword[tg*256 + ((r&15)+16*qt)*4 + t4], byte (r>>4)*2+ih, bits 2d
//   <- adj[rg*32+r][c*1024 + (tg*4+t4)*32 + qt*8 + ih*4 + d]),
// then runs Phase B. Layer 2 re-reads adj: within one graph iteration the
// layer-1 pass leaves adj hot in the 256 MiB L3 (only ~10 MB of traffic
// in between), so pass 2 streams from L3. No packed intermediate at all.
// Grid 2048 = 8 blocks/CU.
// ---------------------------------------------------------------------------
__global__ __launch_bounds__(256, 8) void agg_kernel(
    const int* __restrict__ adj, const half8* __restrict__ Hf,
    float* __restrict__ Zpart) {
  __shared__ char smraw[16384];
  uint* ptile = (uint*)smraw;
  const int tid = threadIdx.x;
  const int rg = blockIdx.x >> 3, c = blockIdx.x & 7;
  const int tg = tid >> 5;            // j-tile-group of 4 tiles
  const int qt = (tid >> 1) & 3;      // quad within tile
  const int t4 = (tid >> 3) & 3;      // tile within group
  const int ih = tid & 1;             // 4-j half of the 8-j quad
  const int byte_base = tg * 1024 + qt * 256 + t4 * 4 + ih;
  unsigned char* pb = (unsigned char*)ptile;
  const size_t gofs = (size_t)rg * 32 * NN + c * 1024 + tid * 4;
#pragma unroll
  for (int r0 = 0; r0 < 32; r0 += 8) {
    int4 a[8];
#pragma unroll
    for (int rr = 0; rr < 8; ++rr)
      a[rr] = *(const int4*)(adj + gofs + (size_t)(r0 + rr) * NN);
#pragma unroll
    for (int rr = 0; rr < 8; ++rr) {
      const int r = r0 + rr;
      const uint b = (uint)(a[rr].x & 3) | ((uint)(a[rr].y & 3) << 2) |
                     ((uint)(a[rr].z & 3) << 4) | ((uint)(a[rr].w & 3) << 6);
      pb[byte_base + (r & 15) * 16 + (r >> 4) * 2] = (unsigned char)b;
    }
  }
  __syncthreads();
  agg_phaseB(ptile, (float*)smraw, Hf, Zpart, rg, c, tid);
}

// ---------------------------------------------------------------------------
// pool_kernel: partials = per-block column sums of relu(sum_{c<8} Zpart + b)
// Grid 32 x 256: block owns 256 rows.
// ---------------------------------------------------------------------------
__global__ __launch_bounds__(256) void pool_kernel(
    const float* __restrict__ Zpart, const float* __restrict__ bias,
    float* __restrict__ partials) {
  const int tid = threadIdx.x;
  const int col = tid & 31, ro = tid >> 5;
  const float b = bias[col];
  float s = 0.f;
  for (int rr = 0; rr < 32; ++rr) {
    const size_t r = (size_t)blockIdx.x * 256 + ro * 32 + rr;
    float v = b;
#pragma unroll
    for (int c = 0; c < 8; ++c) v += Zpart[(size_t)c * NN * 32 + r * 32 + col];
    s += v > 0.f ? v : 0.f;
  }
  __shared__ float red[8][32];
  red[ro][col] = s;
  __syncthreads();
  if (tid < 32) {
    float t = 0.f;
#pragma unroll
    for (int i = 0; i < 8; ++i) t += red[i][tid];
    partials[(size_t)blockIdx.x * 32 + tid] = t;
  }
}

// ---------------------------------------------------------------------------
// fc_kernel: reduce pooled partials (np x 32), fc0+relu, fc1, sigmoid
// ---------------------------------------------------------------------------
__global__ __launch_bounds__(256) void fc_kernel(
    const float* __restrict__ partials, int np, const float* __restrict__ W0,
    const float* __restrict__ b0, const float* __restrict__ W1,
    const float* __restrict__ b1, float* __restrict__ out) {
  __shared__ float acc8[8][32];
  __shared__ float z[32], y[32];
  const int tid = threadIdx.x;
  const int col = tid & 31, ch = tid >> 5;
  float s = 0.f;
  for (int i = ch; i < np; i += 8) s += partials[(size_t)i * 32 + col];
  acc8[ch][col] = s;
  __syncthreads();
  if (tid < 32) {
    float t = 0.f;
#pragma unroll
    for (int i = 0; i < 8; ++i) t += acc8[i][tid];
    z[tid] = t;
  }
  __syncthreads();
  if (tid < 32) {
    float acc = b0[tid];
    for (int n = 0; n < 32; ++n) acc += W0[tid * 32 + n] * z[n];
    y[tid] = acc > 0.f ? acc : 0.f;
  }
  __syncthreads();
  if (tid == 0) {
    float acc = b1[0];
    for (int mm = 0; mm < 32; ++mm) acc += W1[mm] * y[mm];
    out[0] = 1.f / (1.f + expf(-acc));
  }
}

extern "C" void kernel_launch(void* const* d_in, const int* in_sizes, int n_in,
                              void* d_out, int out_size, void* d_ws,
                              size_t ws_size, hipStream_t stream) {
  const float* V   = (const float*)d_in[0];
  const int*   adj = (const int*)d_in[1];
  const float *w10 = (const float*)d_in[2], *w20 = (const float*)d_in[3],
              *w30 = (const float*)d_in[4], *gb0 = (const float*)d_in[5];
  const float *w11 = (const float*)d_in[6], *w21 = (const float*)d_in[7],
              *w31 = (const float*)d_in[8], *gb1 = (const float*)d_in[9];
  const float *fW0 = (const float*)d_in[10], *fb0 = (const float*)d_in[11],
              *fW1 = (const float*)d_in[12], *fb1 = (const float*)d_in[13];
  float* out = (float*)d_out;
  char* ws = (char*)d_ws;

  _Float16* Hfrag    = (_Float16*)ws;                 // 1,572,864 B
  float*    Zpart    = (float*)(ws + 1572864);        // 8,388,608 B
  float*    partials = (float*)(ws + 9961472);        //   262,144 B

  h_kernel<0><<<dim3(128, 3), 256, 0, stream>>>(V, w10, w20, w30, nullptr,
                                                Hfrag);
  agg_kernel<<<2048, 256, 0, stream>>>(adj, (const half8*)Hfrag, Zpart);
  h_kernel<1><<<dim3(128, 3), 256, 0, stream>>>(Zpart, w11, w21, w31, gb0,
                                                Hfrag);
  agg_kernel<<<2048, 256, 0, stream>>>(adj, (const half8*)Hfrag, Zpart);
  pool_kernel<<<32, 256, 0, stream>>>(Zpart, gb1, partials);
  fc_kernel<<<1, 256, 0, stream>>>(partials, 32, fW0, fb0, fW1, fb1, out);
}

// Round 8
// 440.423 us; speedup vs baseline: 1.1060x; 1.1060x over previous
//
#include <hip/hip_runtime.h>
#include <cmath>

#define NN 8192

typedef _Float16 half8 __attribute__((ext_vector_type(8)));
typedef float floatx4 __attribute__((ext_vector_type(4)));
typedef unsigned int uint;

// ---------------------------------------------------------------------------
// h_kernel<L2>: H[ch] = X @ w_ch, output fp16 in MFMA B-fragment order:
//   Hfrag[ch][t][tile][lane][elem], t=j>>5, lane=(n&15)|(((j&31)>>3)<<4),
//   tile=n>>4, elem=j&7.
// L2=0: X = V (f32 [8192,32]).  L2=1: X = relu(sum_{c<8} Zpart[c] + gbias).
// Grid dim3(128,3): blockIdx.y = channel, block owns 64 rows of X.
// ---------------------------------------------------------------------------
template <int L2>
__global__ __launch_bounds__(256) void h_kernel(
    const float* __restrict__ X, const float* __restrict__ w1,
    const float* __restrict__ w2, const float* __restrict__ w3,
    const float* __restrict__ gbias, _Float16* __restrict__ Hfrag) {
  __shared__ float wl[32][32];   // wl[d][n]
  __shared__ float Xs[64][32];
  const int tid = threadIdx.x;
  const int ch = blockIdx.y;
  const float* wsrc = (ch == 0) ? w1 : (ch == 1) ? w2 : w3;
  for (int i = tid; i < 1024; i += 256) ((float*)wl)[i] = wsrc[i];
  const size_t base = (size_t)blockIdx.x * 2048 + tid * 8;
  if (L2 == 0) {
    float4 x0 = ((const float4*)(X + base))[0];
    float4 x1 = ((const float4*)(X + base))[1];
    *((float4*)(&Xs[0][0] + tid * 8)) = x0;
    *((float4*)(&Xs[0][0] + tid * 8 + 4)) = x1;
  } else {
    float4 s0 = {0.f, 0.f, 0.f, 0.f}, s1 = {0.f, 0.f, 0.f, 0.f};
#pragma unroll
    for (int c = 0; c < 8; ++c) {
      const float4* p = (const float4*)(X + (size_t)c * NN * 32 + base);
      float4 a = p[0], b = p[1];
      s0.x += a.x; s0.y += a.y; s0.z += a.z; s0.w += a.w;
      s1.x += b.x; s1.y += b.y; s1.z += b.z; s1.w += b.w;
    }
    const int c0 = (tid * 8) & 31;
    const float4 b0 = *(const float4*)(gbias + c0);
    const float4 b1 = *(const float4*)(gbias + c0 + 4);
    s0.x += b0.x; s0.y += b0.y; s0.z += b0.z; s0.w += b0.w;
    s1.x += b1.x; s1.y += b1.y; s1.z += b1.z; s1.w += b1.w;
    s0.x = s0.x > 0.f ? s0.x : 0.f; s0.y = s0.y > 0.f ? s0.y : 0.f;
    s0.z = s0.z > 0.f ? s0.z : 0.f; s0.w = s0.w > 0.f ? s0.w : 0.f;
    s1.x = s1.x > 0.f ? s1.x : 0.f; s1.y = s1.y > 0.f ? s1.y : 0.f;
    s1.z = s1.z > 0.f ? s1.z : 0.f; s1.w = s1.w > 0.f ? s1.w : 0.f;
    *((float4*)(&Xs[0][0] + tid * 8)) = s0;
    *((float4*)(&Xs[0][0] + tid * 8 + 4)) = s1;
  }
  __syncthreads();
  const int n = tid & 31, jb = tid >> 5;
  const int j0 = blockIdx.x * 64 + jb * 8;
  const int t = j0 >> 5;
  const int lane = (n & 15) | (((j0 & 31) >> 3) << 4);
  const int tile = n >> 4;
  half8 hv;
#pragma unroll
  for (int jj = 0; jj < 8; ++jj) {
    const float4* xr = (const float4*)(&Xs[jb * 8 + jj][0]);
    float acc = 0.f;
#pragma unroll
    for (int d4 = 0; d4 < 8; ++d4) {
      float4 x = xr[d4];
      acc += x.x * wl[d4 * 4 + 0][n];
      acc += x.y * wl[d4 * 4 + 1][n];
      acc += x.z * wl[d4 * 4 + 2][n];
      acc += x.w * wl[d4 * 4 + 3][n];
    }
    hv[jj] = (_Float16)acc;
  }
  size_t idx = ((((size_t)ch * 256 + t) * 2 + tile) * 64 + lane) * 8;
  *(half8*)(Hfrag + idx) = hv;
}

// ---------------------------------------------------------------------------
// phaseB_core: software-pipelined MFMA loop. mk[8] (consume-order mask words,
// uint = rowgrp0 | rowgrp1<<16) already in registers. Per k-tile: prefetch
// NEXT tile's 6 Hf B-fragments, build masks for current, 12 MFMA, rotate.
// Issue->wait distance ~300 cy covers the L2 latency that serialized r4-r7
// phase B. Needs ~90 VGPRs -> callers use __launch_bounds__(256,4).
// Epilogue: 4-wave LDS reduce, raw partials -> Zpart[c][row][32]
// (C/D layout verified: col=lane&15, row=(lane>>4)*4+reg).
// red_raw may alias the agg1 ptile: caller syncs after mk loads.
// ---------------------------------------------------------------------------
__device__ __forceinline__ void phaseB_core(const uint* mk,
                                            const half8* __restrict__ Hf,
                                            float* red_raw,
                                            float* __restrict__ Zpart, int rg,
                                            int c, int tid) {
  const int w = tid >> 6, lane = tid & 63;
  const int m = lane & 15, q = lane >> 4;
  const half8* hp = Hf + (size_t)(c * 32 + w * 8) * 128 + lane;
  // prologue: tile 0 fragments
  half8 b00 = hp[0],     b01 = hp[64];
  half8 b10 = hp[32768], b11 = hp[32768 + 64];
  half8 b20 = hp[65536], b21 = hp[65536 + 64];
  floatx4 acc00 = {0.f, 0.f, 0.f, 0.f}, acc01 = {0.f, 0.f, 0.f, 0.f};
  floatx4 acc10 = {0.f, 0.f, 0.f, 0.f}, acc11 = {0.f, 0.f, 0.f, 0.f};
#pragma unroll
  for (int tl = 0; tl < 8; ++tl) {
    half8 n00, n01, n10, n11, n20, n21;
    if (tl < 7) {  // prefetch next tile while we chew on this one
      const half8* np = hp + (tl + 1) * 128;
      n00 = np[0];     n01 = np[64];
      n10 = np[32768]; n11 = np[32768 + 64];
      n20 = np[65536]; n21 = np[65536 + 64];
    }
    const uint pk = mk[tl];
    half8 a1r0, a2r0, a3r0, a1r1, a2r1, a3r1;
#pragma unroll
    for (int i = 0; i < 8; ++i) {
      const int p0 = (pk >> (2 * i)) & 3;
      const int p1 = (pk >> (16 + 2 * i)) & 3;
      a1r0[i] = (p0 == 1) ? (_Float16)1.f : (_Float16)0.f;
      a2r0[i] = (p0 == 2) ? (_Float16)1.f : (_Float16)0.f;
      a3r0[i] = (p0 == 3) ? (_Float16)1.f : (_Float16)0.f;
      a1r1[i] = (p1 == 1) ? (_Float16)1.f : (_Float16)0.f;
      a2r1[i] = (p1 == 2) ? (_Float16)1.f : (_Float16)0.f;
      a3r1[i] = (p1 == 3) ? (_Float16)1.f : (_Float16)0.f;
    }
    acc00 = __builtin_amdgcn_mfma_f32_16x16x32_f16(a1r0, b00, acc00, 0, 0, 0);
    acc00 = __builtin_amdgcn_mfma_f32_16x16x32_f16(a2r0, b10, acc00, 0, 0, 0);
    acc00 = __builtin_amdgcn_mfma_f32_16x16x32_f16(a3r0, b20, acc00, 0, 0, 0);
    acc01 = __builtin_amdgcn_mfma_f32_16x16x32_f16(a1r0, b01, acc01, 0, 0, 0);
    acc01 = __builtin_amdgcn_mfma_f32_16x16x32_f16(a2r0, b11, acc01, 0, 0, 0);
    acc01 = __builtin_amdgcn_mfma_f32_16x16x32_f16(a3r0, b21, acc01, 0, 0, 0);
    acc10 = __builtin_amdgcn_mfma_f32_16x16x32_f16(a1r1, b00, acc10, 0, 0, 0);
    acc10 = __builtin_amdgcn_mfma_f32_16x16x32_f16(a2r1, b10, acc10, 0, 0, 0);
    acc10 = __builtin_amdgcn_mfma_f32_16x16x32_f16(a3r1, b20, acc10, 0, 0, 0);
    acc11 = __builtin_amdgcn_mfma_f32_16x16x32_f16(a1r1, b01, acc11, 0, 0, 0);
    acc11 = __builtin_amdgcn_mfma_f32_16x16x32_f16(a2r1, b11, acc11, 0, 0, 0);
    acc11 = __builtin_amdgcn_mfma_f32_16x16x32_f16(a3r1, b21, acc11, 0, 0, 0);
    if (tl < 7) {
      b00 = n00; b01 = n01; b10 = n10; b11 = n11; b20 = n20; b21 = n21;
    }
  }
  // combine the 4 waves' j-slices through LDS
  float (*red)[4][64][4] = (float (*)[4][64][4])red_raw;
#pragma unroll
  for (int r = 0; r < 4; ++r) {
    red[w][0][lane][r] = acc00[r];
    red[w][1][lane][r] = acc01[r];
    red[w][2][lane][r] = acc10[r];
    red[w][3][lane][r] = acc11[r];
  }
  __syncthreads();
  if (w == 0) {
    const int rbase = rg * 32;
#pragma unroll
    for (int r = 0; r < 4; ++r) {
      const float c00 = red[0][0][lane][r] + red[1][0][lane][r] +
                        red[2][0][lane][r] + red[3][0][lane][r];
      const float c01 = red[0][1][lane][r] + red[1][1][lane][r] +
                        red[2][1][lane][r] + red[3][1][lane][r];
      const float c10 = red[0][2][lane][r] + red[1][2][lane][r] +
                        red[2][2][lane][r] + red[3][2][lane][r];
      const float c11 = red[0][3][lane][r] + red[1][3][lane][r] +
                        red[2][3][lane][r] + red[3][3][lane][r];
      const int ro0 = rbase + q * 4 + r;
      float* zp0 = Zpart + ((size_t)c * NN + ro0) * 32;
      zp0[m] = c00;
      zp0[16 + m] = c01;
      float* zp1 = Zpart + ((size_t)c * NN + ro0 + 16) * 32;
      zp1[m] = c10;
      zp1[16 + m] = c11;
    }
  }
}

// ---------------------------------------------------------------------------
// agg1_kernel (layer 1, fused pack): block (rg,c) reads adj rows rg*32..+32,
// j c*1024..+1024 with contiguous dwordx4 loads (8 rows in flight/thread),
// packs 2-bit codes into the 8KB LDS consume-order tile (verified layout:
//   dword[tg*256 + ((r&15)+16*qt)*4 + t4], byte (r>>4)*2+ih, bits 2d
//   <- adj[rg*32+r][c*1024 + (tg*4+t4)*32 + qt*8 + ih*4 + d]),
// dumps the tile to packed_g as one contiguous 8KB run for layer 2, then
// runs pipelined phase B. Grid 2048; (256,4) -> 4 blocks/CU, ~128 VGPRs.
// ---------------------------------------------------------------------------
__global__ __launch_bounds__(256, 4) void agg1_kernel(
    const int* __restrict__ adj, uint* __restrict__ packed_g,
    const half8* __restrict__ Hf, float* __restrict__ Zpart) {
  __shared__ char smraw[16384];
  uint* ptile = (uint*)smraw;
  const int tid = threadIdx.x;
  const int rg = blockIdx.x >> 3, c = blockIdx.x & 7;
  const int tg = tid >> 5;            // j-tile-group of 4 tiles
  const int qt = (tid >> 1) & 3;      // quad within tile
  const int t4 = (tid >> 3) & 3;      // tile within group
  const int ih = tid & 1;             // 4-j half of the 8-j quad
  const int byte_base = tg * 1024 + qt * 256 + t4 * 4 + ih;
  unsigned char* pb = (unsigned char*)ptile;
  const size_t gofs = (size_t)rg * 32 * NN + c * 1024 + tid * 4;
#pragma unroll
  for (int r0 = 0; r0 < 32; r0 += 8) {
    int4 a[8];
#pragma unroll
    for (int rr = 0; rr < 8; ++rr)
      a[rr] = *(const int4*)(adj + gofs + (size_t)(r0 + rr) * NN);
#pragma unroll
    for (int rr = 0; rr < 8; ++rr) {
      const int r = r0 + rr;
      const uint b = (uint)(a[rr].x & 3) | ((uint)(a[rr].y & 3) << 2) |
                     ((uint)(a[rr].z & 3) << 4) | ((uint)(a[rr].w & 3) << 6);
      pb[byte_base + (r & 15) * 16 + (r >> 4) * 2] = (unsigned char)b;
    }
  }
  __syncthreads();
  // contiguous 8KB packed write for layer 2
  uint* pg = packed_g + (size_t)blockIdx.x * 2048;
  *(uint4*)(pg + tid * 8) = *(const uint4*)(ptile + tid * 8);
  *(uint4*)(pg + tid * 8 + 4) = *(const uint4*)(ptile + tid * 8 + 4);
  // mask words into registers, then free ptile for the reduce buffer
  const int w = tid >> 6, lane = tid & 63;
  uint mk[8];
  *(uint4*)(mk) = *(const uint4*)(ptile + (w * 2) * 256 + lane * 4);
  *(uint4*)(mk + 4) = *(const uint4*)(ptile + (w * 2 + 1) * 256 + lane * 4);
  __syncthreads();
  phaseB_core(mk, Hf, (float*)smraw, Zpart, rg, c, tid);
}

// ---------------------------------------------------------------------------
// agg2_kernel (layer 2): mask words straight from the packed buffer
// (consume-order => 16B/lane coalesced dwordx4, L2/L3-resident; no LDS
// staging), then pipelined phase B.
// ---------------------------------------------------------------------------
__global__ __launch_bounds__(256, 4) void agg2_kernel(
    const uint* __restrict__ packed_g, const half8* __restrict__ Hf,
    float* __restrict__ Zpart) {
  __shared__ float red_lds[4][4][64][4];
  const int tid = threadIdx.x;
  const int rg = blockIdx.x >> 3, c = blockIdx.x & 7;
  const int w = tid >> 6, lane = tid & 63;
  const uint* pg =
      packed_g + (size_t)blockIdx.x * 2048 + (w * 2) * 256 + lane * 4;
  uint mk[8];
  *(uint4*)(mk) = *(const uint4*)(pg);
  *(uint4*)(mk + 4) = *(const uint4*)(pg + 256);
  phaseB_core(mk, Hf, (float*)red_lds, Zpart, rg, c, tid);
}

// ---------------------------------------------------------------------------
// pool_kernel: partials = per-block column sums of relu(sum_{c<8} Zpart + b)
// Grid 32 x 256: block owns 256 rows.
// ---------------------------------------------------------------------------
__global__ __launch_bounds__(256) void pool_kernel(
    const float* __restrict__ Zpart, const float* __restrict__ bias,
    float* __restrict__ partials) {
  const int tid = threadIdx.x;
  const int col = tid & 31, ro = tid >> 5;
  const float b = bias[col];
  float s = 0.f;
  for (int rr = 0; rr < 32; ++rr) {
    const size_t r = (size_t)blockIdx.x * 256 + ro * 32 + rr;
    float v = b;
#pragma unroll
    for (int c = 0; c < 8; ++c) v += Zpart[(size_t)c * NN * 32 + r * 32 + col];
    s += v > 0.f ? v : 0.f;
  }
  __shared__ float red[8][32];
  red[ro][col] = s;
  __syncthreads();
  if (tid < 32) {
    float t = 0.f;
#pragma unroll
    for (int i = 0; i < 8; ++i) t += red[i][tid];
    partials[(size_t)blockIdx.x * 32 + tid] = t;
  }
}

// ---------------------------------------------------------------------------
// fc_kernel: reduce pooled partials (np x 32), fc0+relu, fc1, sigmoid
// ---------------------------------------------------------------------------
__global__ __launch_bounds__(256) void fc_kernel(
    const float* __restrict__ partials, int np, const float* __restrict__ W0,
    const float* __restrict__ b0, const float* __restrict__ W1,
    const float* __restrict__ b1, float* __restrict__ out) {
  __shared__ float acc8[8][32];
  __shared__ float z[32], y[32];
  const int tid = threadIdx.x;
  const int col = tid & 31, ch = tid >> 5;
  float s = 0.f;
  for (int i = ch; i < np; i += 8) s += partials[(size_t)i * 32 + col];
  acc8[ch][col] = s;
  __syncthreads();
  if (tid < 32) {
    float t = 0.f;
#pragma unroll
    for (int i = 0; i < 8; ++i) t += acc8[i][tid];
    z[tid] = t;
  }
  __syncthreads();
  if (tid < 32) {
    float acc = b0[tid];
    for (int n = 0; n < 32; ++n) acc += W0[tid * 32 + n] * z[n];
    y[tid] = acc > 0.f ? acc : 0.f;
  }
  __syncthreads();
  if (tid == 0) {
    float acc = b1[0];
    for (int mm = 0; mm < 32; ++mm) acc += W1[mm] * y[mm];
    out[0] = 1.f / (1.f + expf(-acc));
  }
}

extern "C" void kernel_launch(void* const* d_in, const int* in_sizes, int n_in,
                              void* d_out, int out_size, void* d_ws,
                              size_t ws_size, hipStream_t stream) {
  const float* V   = (const float*)d_in[0];
  const int*   adj = (const int*)d_in[1];
  const float *w10 = (const float*)d_in[2], *w20 = (const float*)d_in[3],
              *w30 = (const float*)d_in[4], *gb0 = (const float*)d_in[5];
  const float *w11 = (const float*)d_in[6], *w21 = (const float*)d_in[7],
              *w31 = (const float*)d_in[8], *gb1 = (const float*)d_in[9];
  const float *fW0 = (const float*)d_in[10], *fb0 = (const float*)d_in[11],
              *fW1 = (const float*)d_in[12], *fb1 = (const float*)d_in[13];
  float* out = (float*)d_out;
  char* ws = (char*)d_ws;

  _Float16* Hfrag    = (_Float16*)ws;                 // 1,572,864 B
  float*    Zpart    = (float*)(ws + 1572864);        // 8,388,608 B
  float*    partials = (float*)(ws + 9961472);        //   262,144 B
  uint*     packed   = (uint*)(ws + 10223616);        // 16,777,216 B

  h_kernel<0><<<dim3(128, 3), 256, 0, stream>>>(V, w10, w20, w30, nullptr,
                                                Hfrag);
  agg1_kernel<<<2048, 256, 0, stream>>>(adj, packed, (const half8*)Hfrag,
                                        Zpart);
  h_kernel<1><<<dim3(128, 3), 256, 0, stream>>>(Zpart, w11, w21, w31, gb0,
                                                Hfrag);
  agg2_kernel<<<2048, 256, 0, stream>>>(packed, (const half8*)Hfrag, Zpart);
  pool_kernel<<<32, 256, 0, stream>>>(Zpart, gb1, partials);
  fc_kernel<<<1, 256, 0, stream>>>(partials, 32, fW0, fb0, fW1, fb1, out);
}